// Round 3
// baseline (158.707 us; speedup 1.0000x reference)
//
#include <hip/hip_runtime.h>
#include <math.h>

// NormalLoss: for each template vertex (M=6890), take the K=15 scan points
// (N=20000) with LARGEST distance, among them pick the min-angle normal
// match, loss = mean ||sv[sel]-tv||.
//
// Round-3 design (round-2 was correct; prep was the bottleneck):
//  * prep split into 3 parallel kernels: histogram (multi-block, global
//    atomics), scan (1 block: bucket prefix-sum -> cursors + per-64-block
//    suffix |p| upper bound from bucket edges), scatter (multi-block, global
//    cursor atomics). Within-bucket order is nondeterministic -- harmless:
//    all tie-breaks are explicit on (d2, original idx), and smax uses
//    order-independent bucket upper edges.
//  * main kernel (unchanged from round 2): one wave per vertex, bitonic
//    bootstrap over first 64 sorted points, ballot+popcount sorted inserts,
//    early break when (suffixBound|p| + |tv|)^2 < current 15th-largest d^2.

constexpr int K = 15;
constexpr int NBUCK = 256;
constexpr int WAVES = 4;     // waves (=vertices) per block in main kernel

__device__ __forceinline__ int bucket_of(float k2) {
    int b = (int)(k2 * 8.0f);           // 0.125-wide buckets over |p|^2 in [0,32)
    b = b > (NBUCK - 1) ? (NBUCK - 1) : b;
    return (NBUCK - 1) - b;             // bucket 0 = largest |p|
}

__global__ void zero_out_kernel(float* out) { out[0] = 0.0f; }

__global__ __launch_bounds__(256) void hist_kernel(
    const float* __restrict__ sv, int* __restrict__ hist, int N)
{
    int i = blockIdx.x * blockDim.x + threadIdx.x;
    if (i < N) {
        float x = sv[3*i], y = sv[3*i+1], z = sv[3*i+2];
        atomicAdd(&hist[bucket_of(fmaf(x, x, fmaf(y, y, z*z)))], 1);
    }
}

__global__ __launch_bounds__(256) void scan_kernel(
    const int* __restrict__ hist,
    int*       __restrict__ cursor,  // [NBUCK] out: bucket start positions
    float*     __restrict__ smax,    // [nb] out: upper bound on |p| at pos >= j*64
    float*     __restrict__ out,     // zeroed here (main kernel atomicAdds)
    int nb)
{
    __shared__ int tmp[NBUCK];
    __shared__ int start[NBUCK];     // exclusive prefix = bucket start position
    int t = threadIdx.x;
    if (t == 0) out[0] = 0.0f;

    int h = hist[t];
    tmp[t] = h;
    __syncthreads();
    for (int d = 1; d < NBUCK; d <<= 1) {
        int u = (t >= d) ? tmp[t - d] : 0;
        __syncthreads();
        tmp[t] += u;
        __syncthreads();
    }
    start[t] = tmp[t] - h;           // exclusive
    cursor[t] = tmp[t] - h;
    __syncthreads();

    // smax[j]: position j*64 lies in bucket fb (largest fb with start[fb] <= pos);
    // every point at position >= j*64 is in bucket >= fb (flipped order), so
    // |p| <= sqrt(upper edge of fb's |p|^2 range). Exact upper bound.
    for (int j = t; j < nb; j += 256) {
        int pos = j * 64;
        int lo = 0, hi = NBUCK - 1;
        while (lo < hi) {
            int mid = (lo + hi + 1) >> 1;
            if (start[mid] <= pos) lo = mid; else hi = mid - 1;
        }
        int bOrig = (NBUCK - 1) - lo;            // original (unflipped) bucket
        smax[j] = sqrtf((float)(bOrig + 1) * 0.125f);
    }
}

__global__ __launch_bounds__(256) void scatter_kernel(
    const float* __restrict__ sv,
    int*         __restrict__ cursor,
    float4*      __restrict__ sorted,  // [N] out: (x,y,z,bitcast(origIdx))
    int N)
{
    int i = blockIdx.x * blockDim.x + threadIdx.x;
    if (i < N) {
        float x = sv[3*i], y = sv[3*i+1], z = sv[3*i+2];
        float k2 = fmaf(x, x, fmaf(y, y, z*z));
        int pos = atomicAdd(&cursor[bucket_of(k2)], 1);
        sorted[pos] = make_float4(x, y, z, __int_as_float(i));
    }
}

template<bool SORTED>
__global__ __launch_bounds__(WAVES * 64) void knn_loss_kernel(
    const float4* __restrict__ pts,   // sorted points (SORTED only)
    const float*  __restrict__ smax,  // suffix |p| upper bound per 64-block
    const float*  __restrict__ sv,    // [N,3] original scan vertices
    const float*  __restrict__ tv,    // [M,3]
    const float*  __restrict__ sn,    // [N,3]
    const float*  __restrict__ tn,    // [M,3]
    float* __restrict__ out, int N, int M, float invM)
{
    __shared__ float bsum[WAVES];
    const int lane = threadIdx.x & 63;
    const int w    = threadIdx.x >> 6;
    const int m    = blockIdx.x * WAVES + w;
    const bool valid = (m < M);

    float contrib = 0.0f;
    if (valid) {
        const float tvx = tv[3*m], tvy = tv[3*m+1], tvz = tv[3*m+2];
        const float tlen = sqrtf(tvx*tvx + tvy*tvy + tvz*tvz);

        // ---- bootstrap: bitonic-sort first 64 points desc by (d2, -idx) ----
        float v; int idx;
        {
            int l = (lane < N) ? lane : 0;
            float px, py, pz;
            if (SORTED) {
                float4 q = pts[l];
                px = q.x; py = q.y; pz = q.z; idx = __float_as_int(q.w);
            } else {
                px = sv[3*l]; py = sv[3*l+1]; pz = sv[3*l+2]; idx = l;
            }
            float dx = px - tvx, dy = py - tvy, dz = pz - tvz;
            v = fmaf(dx, dx, fmaf(dy, dy, dz * dz));
            if (lane >= N) { v = -1.0f; idx = 0x7FFFFFFF; }
        }
#pragma unroll
        for (int k = 2; k <= 64; k <<= 1) {
#pragma unroll
            for (int j = k >> 1; j > 0; j >>= 1) {
                float ov = __shfl_xor(v, j);
                int   oi = __shfl_xor(idx, j);
                bool up    = ((lane & k) == 0);   // descending segment
                bool lower = ((lane & j) == 0);
                bool mine  = (v > ov) || (v == ov && idx < oi); // total order
                bool keep  = lower ? (up ? mine : !mine) : (up ? !mine : mine);
                if (!keep) { v = ov; idx = oi; }
            }
        }
        // lanes 0..K-1 now hold the exact top-K of the first 64 (sorted desc)
        float eV = (lane < K) ? v : -1.0f;
        int   eI = idx;
        float thr = __shfl(v, K - 1);   // current 15th-largest d2

        // ---- main scan ----
        for (int ib = 64; ib < N; ib += 64) {
            if (SORTED) {
                float bnd = smax[ib >> 6] + tlen;      // upper bound on remaining d
                if (bnd * bnd * 1.00001f < thr) break; // margin covers fp rounding
            }
            int  i   = ib + lane;
            bool has = (i < N);
            float d2; int oi2;
            if (SORTED) {
                float4 q = pts[has ? i : 0];
                float dx = q.x - tvx, dy = q.y - tvy, dz = q.z - tvz;
                d2 = fmaf(dx, dx, fmaf(dy, dy, dz * dz));
                oi2 = __float_as_int(q.w);
            } else {
                int g = has ? i : 0;
                float dx = sv[3*g] - tvx, dy = sv[3*g+1] - tvy, dz = sv[3*g+2] - tvz;
                d2 = fmaf(dx, dx, fmaf(dy, dy, dz * dz));
                oi2 = i;
            }
            // >= : an equal-d2 candidate with lower original idx must displace
            unsigned long long mb = __ballot(has && (d2 >= thr));
            if (mb) {
                do {
                    int src = __ffsll(mb) - 1;
                    mb &= mb - 1;
                    float cv = __shfl(d2, src);
                    int   ci = __shfl(oi2, src);
                    // position = #entries strictly better than candidate
                    unsigned long long bb =
                        __ballot((eV > cv) || (eV == cv && eI < ci)) & 0x7FFFull;
                    int p = __popcll(bb);
                    if (p < K) {   // wave-uniform
                        float uv = __shfl_up(eV, 1);
                        int   ui = __shfl_up(eI, 1);
                        if (lane < K) {
                            if (lane == p)      { eV = cv; eI = ci; }
                            else if (lane > p)  { eV = uv; eI = ui; }
                        }
                    }
                } while (mb);
                thr = __shfl(eV, K - 1);
            }
        }

        // ---- epilogue: argmin angle, tie-break by top-k rank (= lane) ----
        const float tnx = tn[3*m], tny = tn[3*m+1], tnz = tn[3*m+2];
        float ang = 3.0e38f;
        int myI = eI;
        if (lane < K && myI != 0x7FFFFFFF) {
            float dot = sn[3*myI]*tnx + sn[3*myI+1]*tny + sn[3*myI+2]*tnz;
            dot = fminf(1.0f, fmaxf(-1.0f, dot));
            ang = acosf(dot) * 57.29577951308232f;   // degrees, matches jnp
        }
        float ba = ang; int br = lane; int bi = myI;
#pragma unroll
        for (int s = 1; s < 64; s <<= 1) {
            float oa  = __shfl_xor(ba, s);
            int   orr = __shfl_xor(br, s);
            int   oi  = __shfl_xor(bi, s);
            bool take = (oa < ba) || (oa == ba && orr < br);
            if (take) { ba = oa; br = orr; bi = oi; }
        }
        if (lane == 0) {
            float dx = sv[3*bi]   - tvx;
            float dy = sv[3*bi+1] - tvy;
            float dz = sv[3*bi+2] - tvz;
            contrib = sqrtf(dx*dx + dy*dy + dz*dz) * invM;
        }
    }

    if (lane == 0) bsum[w] = contrib;
    __syncthreads();
    if (threadIdx.x == 0) {
        float s = 0.0f;
#pragma unroll
        for (int i = 0; i < WAVES; ++i) s += bsum[i];
        atomicAdd(out, s);
    }
}

extern "C" void kernel_launch(void* const* d_in, const int* in_sizes, int n_in,
                              void* d_out, int out_size, void* d_ws, size_t ws_size,
                              hipStream_t stream) {
    const float* sv = (const float*)d_in[0];   // scan_vertices   [1,N,3]
    const float* tv = (const float*)d_in[1];   // template_vertices [1,M,3]
    const float* sn = (const float*)d_in[2];   // scan_normals    [N,3]
    const float* tn = (const float*)d_in[3];   // template_normals [M,3]
    // d_in[4] = K_knn (fixed 15, compile-time)

    int N = in_sizes[0] / 3;
    int M = in_sizes[1] / 3;
    int nb = (N + 63) / 64;
    float* out = (float*)d_out;
    float invM = 1.0f / (float)M;
    int grid = (M + WAVES - 1) / WAVES;
    int gridN = (N + 255) / 256;

    // d_ws layout: [sorted float4 x N][smax x nb][hist x 256][cursor x 256]
    size_t offSorted = 0;
    size_t offSmax   = offSorted + (size_t)N * sizeof(float4);
    size_t offHist   = (offSmax + (size_t)nb * sizeof(float) + 15) & ~(size_t)15;
    size_t offCursor = offHist + NBUCK * sizeof(int);
    size_t need      = offCursor + NBUCK * sizeof(int);

    if (ws_size >= need) {
        float4* sorted = (float4*)((char*)d_ws + offSorted);
        float*  smax   = (float*) ((char*)d_ws + offSmax);
        int*    hist   = (int*)   ((char*)d_ws + offHist);
        int*    cursor = (int*)   ((char*)d_ws + offCursor);

        hipMemsetAsync(hist, 0, NBUCK * sizeof(int), stream);
        hist_kernel   <<<gridN, 256, 0, stream>>>(sv, hist, N);
        scan_kernel   <<<1,     256, 0, stream>>>(hist, cursor, smax, out, nb);
        scatter_kernel<<<gridN, 256, 0, stream>>>(sv, cursor, sorted, N);
        knn_loss_kernel<true><<<grid, WAVES * 64, 0, stream>>>(
            sorted, smax, sv, tv, sn, tn, out, N, M, invM);
    } else {
        zero_out_kernel<<<1, 1, 0, stream>>>(out);
        knn_loss_kernel<false><<<grid, WAVES * 64, 0, stream>>>(
            nullptr, nullptr, sv, tv, sn, tn, out, N, M, invM);
    }
}

// Round 4
// 105.121 us; speedup vs baseline: 1.5098x; 1.5098x over previous
//
#include <hip/hip_runtime.h>
#include <math.h>

// NormalLoss: for each template vertex (M=6890), take the K=15 scan points
// (N=20000) with LARGEST distance, among them pick the min-angle normal
// match, loss = mean ||sv[sel]-tv||.
//
// Round-4 design (round-3 regressed on global-atomic contention):
//  * hist_kernel: per-block LDS histogram of |p|^2 buckets -> blkhist rows
//    (full overwrite, no memset, no global atomics).
//  * scan_scatter_kernel: each block redundantly column-sums blkhist
//    (coalesced), Kogge-Stone bucket prefix in LDS, derives its own
//    per-bucket write base, scatters its 256 points via LDS cursors.
//    Block 0 also writes smax[] (bucket-edge suffix |p| upper bound,
//    order-independent) and zeroes out[0].
//  * main kernel (unchanged, absmax 0.0 in rounds 2-3): one wave per vertex,
//    bitonic bootstrap over the 64 largest-|p| points, ballot+popcount sorted
//    inserts, early break when (suffixBound|p| + |tv|)^2 < 15th-largest d^2.
//    All tie-breaks explicit on (d2, original idx) -> exact jax semantics,
//    independent of within-bucket scatter order.

constexpr int K = 15;
constexpr int NBUCK = 256;
constexpr int WAVES = 4;     // waves (=vertices) per block in main kernel

__device__ __forceinline__ int bucket_of(float k2) {
    int b = (int)(k2 * 8.0f);           // 0.125-wide buckets over |p|^2 in [0,32)
    b = b > (NBUCK - 1) ? (NBUCK - 1) : b;
    return (NBUCK - 1) - b;             // bucket 0 = largest |p|
}

__global__ void zero_out_kernel(float* out) { out[0] = 0.0f; }

__global__ __launch_bounds__(256) void hist_kernel(
    const float* __restrict__ sv, int* __restrict__ blkhist, int N)
{
    __shared__ int h[NBUCK];
    int t = threadIdx.x;
    h[t] = 0;
    __syncthreads();
    int i = blockIdx.x * 256 + t;
    if (i < N) {
        float x = sv[3*i], y = sv[3*i+1], z = sv[3*i+2];
        atomicAdd(&h[bucket_of(fmaf(x, x, fmaf(y, y, z*z)))], 1);
    }
    __syncthreads();
    blkhist[blockIdx.x * NBUCK + t] = h[t];   // full-row overwrite (poison-safe)
}

__global__ __launch_bounds__(256) void scan_scatter_kernel(
    const float* __restrict__ sv,
    const int*   __restrict__ blkhist,  // [nblk][NBUCK]
    float4*      __restrict__ sorted,   // [N] out: (x,y,z,bitcast(origIdx))
    float*       __restrict__ smax,     // [nb] out: |p| upper bound at pos >= j*64
    float*       __restrict__ out,      // zeroed by block 0
    int N, int nb, int nblk)
{
    __shared__ int tmp[NBUCK];
    __shared__ int startSh[NBUCK];
    __shared__ int cursor[NBUCK];
    const int t   = threadIdx.x;
    const int blk = blockIdx.x;

    // column sums over blocks (coalesced row reads) + my block's base offset
    int mine = 0, total = 0;
    for (int b = 0; b < nblk; ++b) {
        int v = blkhist[b * NBUCK + t];
        if (b < blk) mine += v;
        total += v;
    }
    tmp[t] = total;
    __syncthreads();
    // Kogge-Stone inclusive scan over buckets
    for (int d = 1; d < NBUCK; d <<= 1) {
        int u = (t >= d) ? tmp[t - d] : 0;
        __syncthreads();
        tmp[t] += u;
        __syncthreads();
    }
    int startv = tmp[t] - total;        // exclusive bucket start
    startSh[t] = startv;
    cursor[t]  = startv + mine;         // this block's write base per bucket
    __syncthreads();

    if (blk == 0) {
        if (t == 0) out[0] = 0.0f;
        // smax[j]: position j*64 lies in flipped bucket fb (largest fb with
        // start[fb] <= pos); all points at pos >= j*64 have original bucket
        // <= (NBUCK-1)-fb, so |p| <= sqrt(upper edge). Exact upper bound,
        // independent of within-bucket order.
        for (int j = t; j < nb; j += 256) {
            int pos = j * 64;
            int lo = 0, hi = NBUCK - 1;
            while (lo < hi) {
                int mid = (lo + hi + 1) >> 1;
                if (startSh[mid] <= pos) lo = mid; else hi = mid - 1;
            }
            int bOrig = (NBUCK - 1) - lo;
            smax[j] = sqrtf((float)(bOrig + 1) * 0.125f);
        }
    }

    int i = blk * 256 + t;
    if (i < N) {
        float x = sv[3*i], y = sv[3*i+1], z = sv[3*i+2];
        float k2 = fmaf(x, x, fmaf(y, y, z*z));
        int pos = atomicAdd(&cursor[bucket_of(k2)], 1);   // LDS atomic
        sorted[pos] = make_float4(x, y, z, __int_as_float(i));
    }
}

template<bool SORTED>
__global__ __launch_bounds__(WAVES * 64) void knn_loss_kernel(
    const float4* __restrict__ pts,   // sorted points (SORTED only)
    const float*  __restrict__ smax,  // suffix |p| upper bound per 64-block
    const float*  __restrict__ sv,    // [N,3] original scan vertices
    const float*  __restrict__ tv,    // [M,3]
    const float*  __restrict__ sn,    // [N,3]
    const float*  __restrict__ tn,    // [M,3]
    float* __restrict__ out, int N, int M, float invM)
{
    __shared__ float bsum[WAVES];
    const int lane = threadIdx.x & 63;
    const int w    = threadIdx.x >> 6;
    const int m    = blockIdx.x * WAVES + w;
    const bool valid = (m < M);

    float contrib = 0.0f;
    if (valid) {
        const float tvx = tv[3*m], tvy = tv[3*m+1], tvz = tv[3*m+2];
        const float tlen = sqrtf(tvx*tvx + tvy*tvy + tvz*tvz);

        // ---- bootstrap: bitonic-sort first 64 points desc by (d2, -idx) ----
        float v; int idx;
        {
            int l = (lane < N) ? lane : 0;
            float px, py, pz;
            if (SORTED) {
                float4 q = pts[l];
                px = q.x; py = q.y; pz = q.z; idx = __float_as_int(q.w);
            } else {
                px = sv[3*l]; py = sv[3*l+1]; pz = sv[3*l+2]; idx = l;
            }
            float dx = px - tvx, dy = py - tvy, dz = pz - tvz;
            v = fmaf(dx, dx, fmaf(dy, dy, dz * dz));
            if (lane >= N) { v = -1.0f; idx = 0x7FFFFFFF; }
        }
#pragma unroll
        for (int k = 2; k <= 64; k <<= 1) {
#pragma unroll
            for (int j = k >> 1; j > 0; j >>= 1) {
                float ov = __shfl_xor(v, j);
                int   oi = __shfl_xor(idx, j);
                bool up    = ((lane & k) == 0);   // descending segment
                bool lower = ((lane & j) == 0);
                bool mine  = (v > ov) || (v == ov && idx < oi); // total order
                bool keep  = lower ? (up ? mine : !mine) : (up ? !mine : mine);
                if (!keep) { v = ov; idx = oi; }
            }
        }
        // lanes 0..K-1 now hold the exact top-K of the first 64 (sorted desc)
        float eV = (lane < K) ? v : -1.0f;
        int   eI = idx;
        float thr = __shfl(v, K - 1);   // current 15th-largest d2

        // ---- main scan ----
        for (int ib = 64; ib < N; ib += 64) {
            if (SORTED) {
                float bnd = smax[ib >> 6] + tlen;      // upper bound on remaining d
                if (bnd * bnd * 1.00001f < thr) break; // margin covers fp rounding
            }
            int  i   = ib + lane;
            bool has = (i < N);
            float d2; int oi2;
            if (SORTED) {
                float4 q = pts[has ? i : 0];
                float dx = q.x - tvx, dy = q.y - tvy, dz = q.z - tvz;
                d2 = fmaf(dx, dx, fmaf(dy, dy, dz * dz));
                oi2 = __float_as_int(q.w);
            } else {
                int g = has ? i : 0;
                float dx = sv[3*g] - tvx, dy = sv[3*g+1] - tvy, dz = sv[3*g+2] - tvz;
                d2 = fmaf(dx, dx, fmaf(dy, dy, dz * dz));
                oi2 = i;
            }
            // >= : an equal-d2 candidate with lower original idx must displace
            unsigned long long mb = __ballot(has && (d2 >= thr));
            if (mb) {
                do {
                    int src = __ffsll(mb) - 1;
                    mb &= mb - 1;
                    float cv = __shfl(d2, src);
                    int   ci = __shfl(oi2, src);
                    // position = #entries strictly better than candidate
                    unsigned long long bb =
                        __ballot((eV > cv) || (eV == cv && eI < ci)) & 0x7FFFull;
                    int p = __popcll(bb);
                    if (p < K) {   // wave-uniform
                        float uv = __shfl_up(eV, 1);
                        int   ui = __shfl_up(eI, 1);
                        if (lane < K) {
                            if (lane == p)      { eV = cv; eI = ci; }
                            else if (lane > p)  { eV = uv; eI = ui; }
                        }
                    }
                } while (mb);
                thr = __shfl(eV, K - 1);
            }
        }

        // ---- epilogue: argmin angle, tie-break by top-k rank (= lane) ----
        const float tnx = tn[3*m], tny = tn[3*m+1], tnz = tn[3*m+2];
        float ang = 3.0e38f;
        int myI = eI;
        if (lane < K && myI != 0x7FFFFFFF) {
            float dot = sn[3*myI]*tnx + sn[3*myI+1]*tny + sn[3*myI+2]*tnz;
            dot = fminf(1.0f, fmaxf(-1.0f, dot));
            ang = acosf(dot) * 57.29577951308232f;   // degrees, matches jnp
        }
        float ba = ang; int br = lane; int bi = myI;
#pragma unroll
        for (int s = 1; s < 64; s <<= 1) {
            float oa  = __shfl_xor(ba, s);
            int   orr = __shfl_xor(br, s);
            int   oi  = __shfl_xor(bi, s);
            bool take = (oa < ba) || (oa == ba && orr < br);
            if (take) { ba = oa; br = orr; bi = oi; }
        }
        if (lane == 0) {
            float dx = sv[3*bi]   - tvx;
            float dy = sv[3*bi+1] - tvy;
            float dz = sv[3*bi+2] - tvz;
            contrib = sqrtf(dx*dx + dy*dy + dz*dz) * invM;
        }
    }

    if (lane == 0) bsum[w] = contrib;
    __syncthreads();
    if (threadIdx.x == 0) {
        float s = 0.0f;
#pragma unroll
        for (int i = 0; i < WAVES; ++i) s += bsum[i];
        atomicAdd(out, s);
    }
}

extern "C" void kernel_launch(void* const* d_in, const int* in_sizes, int n_in,
                              void* d_out, int out_size, void* d_ws, size_t ws_size,
                              hipStream_t stream) {
    const float* sv = (const float*)d_in[0];   // scan_vertices   [1,N,3]
    const float* tv = (const float*)d_in[1];   // template_vertices [1,M,3]
    const float* sn = (const float*)d_in[2];   // scan_normals    [N,3]
    const float* tn = (const float*)d_in[3];   // template_normals [M,3]
    // d_in[4] = K_knn (fixed 15, compile-time)

    int N = in_sizes[0] / 3;
    int M = in_sizes[1] / 3;
    int nb = (N + 63) / 64;
    float* out = (float*)d_out;
    float invM = 1.0f / (float)M;
    int grid  = (M + WAVES - 1) / WAVES;
    int nblk  = (N + 255) / 256;

    // d_ws layout: [sorted float4 x N][smax x nb][blkhist x nblk*256]
    size_t offSorted = 0;
    size_t offSmax   = offSorted + (size_t)N * sizeof(float4);
    size_t offHist   = (offSmax + (size_t)nb * sizeof(float) + 15) & ~(size_t)15;
    size_t need      = offHist + (size_t)nblk * NBUCK * sizeof(int);

    if (ws_size >= need) {
        float4* sorted  = (float4*)((char*)d_ws + offSorted);
        float*  smax    = (float*) ((char*)d_ws + offSmax);
        int*    blkhist = (int*)   ((char*)d_ws + offHist);

        hist_kernel        <<<nblk, 256, 0, stream>>>(sv, blkhist, N);
        scan_scatter_kernel<<<nblk, 256, 0, stream>>>(sv, blkhist, sorted,
                                                      smax, out, N, nb, nblk);
        knn_loss_kernel<true><<<grid, WAVES * 64, 0, stream>>>(
            sorted, smax, sv, tv, sn, tn, out, N, M, invM);
    } else {
        zero_out_kernel<<<1, 1, 0, stream>>>(out);
        knn_loss_kernel<false><<<grid, WAVES * 64, 0, stream>>>(
            nullptr, nullptr, sv, tv, sn, tn, out, N, M, invM);
    }
}

// Round 5
// 97.590 us; speedup vs baseline: 1.6263x; 1.0772x over previous
//
#include <hip/hip_runtime.h>
#include <math.h>

// NormalLoss: for each template vertex (M=6890), take the K=15 scan points
// (N=20000) with LARGEST distance, among them pick the min-angle normal
// match, loss = mean ||sv[sel]-tv||.
//
// Round-5 design (round-4 main kernel was latency-bound on an insert-event
// avalanche: ballot computed vs stale thr let ~25-30 doomed candidates per
// early block each fire a ~300-500 cyc serialized cross-lane event):
//  * main kernel: thr is re-tightened and the candidate mask re-balloted
//    after EVERY accepted insert -> processed events ~= accepted inserts.
//    Epilogue argmin reduced over 16 lanes (entries live in lanes 0..14).
//  * scan_scatter: unroll the blkhist column-sum so L2 loads pipeline.
//  * structure otherwise identical to round 4 (absmax 0.0 three rounds
//    running): hist (LDS, per-block rows) -> scan_scatter (redundant scan,
//    LDS cursors) -> main (bitonic bootstrap, sorted wave top-K, early
//    break when (suffixBound|p| + |tv|)^2 < 15th-largest d^2).

constexpr int K = 15;
constexpr int NBUCK = 256;
constexpr int WAVES = 4;     // waves (=vertices) per block in main kernel

__device__ __forceinline__ int bucket_of(float k2) {
    int b = (int)(k2 * 8.0f);           // 0.125-wide buckets over |p|^2 in [0,32)
    b = b > (NBUCK - 1) ? (NBUCK - 1) : b;
    return (NBUCK - 1) - b;             // bucket 0 = largest |p|
}

__global__ void zero_out_kernel(float* out) { out[0] = 0.0f; }

__global__ __launch_bounds__(256) void hist_kernel(
    const float* __restrict__ sv, int* __restrict__ blkhist, int N)
{
    __shared__ int h[NBUCK];
    int t = threadIdx.x;
    h[t] = 0;
    __syncthreads();
    int i = blockIdx.x * 256 + t;
    if (i < N) {
        float x = sv[3*i], y = sv[3*i+1], z = sv[3*i+2];
        atomicAdd(&h[bucket_of(fmaf(x, x, fmaf(y, y, z*z)))], 1);
    }
    __syncthreads();
    blkhist[blockIdx.x * NBUCK + t] = h[t];   // full-row overwrite (poison-safe)
}

__global__ __launch_bounds__(256) void scan_scatter_kernel(
    const float* __restrict__ sv,
    const int*   __restrict__ blkhist,  // [nblk][NBUCK]
    float4*      __restrict__ sorted,   // [N] out: (x,y,z,bitcast(origIdx))
    float*       __restrict__ smax,     // [nb] out: |p| upper bound at pos >= j*64
    float*       __restrict__ out,      // zeroed by block 0
    int N, int nb, int nblk)
{
    __shared__ int tmp[NBUCK];
    __shared__ int startSh[NBUCK];
    __shared__ int cursor[NBUCK];
    const int t   = threadIdx.x;
    const int blk = blockIdx.x;

    // column sums over blocks (coalesced row reads); unrolled so the L2
    // loads pipeline instead of serializing on ~300-cyc latency
    int mine = 0, total = 0;
#pragma unroll 8
    for (int b = 0; b < nblk; ++b) {
        int v = blkhist[b * NBUCK + t];
        if (b < blk) mine += v;
        total += v;
    }
    tmp[t] = total;
    __syncthreads();
    // Kogge-Stone inclusive scan over buckets
    for (int d = 1; d < NBUCK; d <<= 1) {
        int u = (t >= d) ? tmp[t - d] : 0;
        __syncthreads();
        tmp[t] += u;
        __syncthreads();
    }
    int startv = tmp[t] - total;        // exclusive bucket start
    startSh[t] = startv;
    cursor[t]  = startv + mine;         // this block's write base per bucket
    __syncthreads();

    if (blk == 0) {
        if (t == 0) out[0] = 0.0f;
        // smax[j]: position j*64 lies in flipped bucket fb (largest fb with
        // start[fb] <= pos); all points at pos >= j*64 have original bucket
        // <= (NBUCK-1)-fb, so |p| <= sqrt(upper edge). Exact upper bound,
        // independent of within-bucket order.
        for (int j = t; j < nb; j += 256) {
            int pos = j * 64;
            int lo = 0, hi = NBUCK - 1;
            while (lo < hi) {
                int mid = (lo + hi + 1) >> 1;
                if (startSh[mid] <= pos) lo = mid; else hi = mid - 1;
            }
            int bOrig = (NBUCK - 1) - lo;
            smax[j] = sqrtf((float)(bOrig + 1) * 0.125f);
        }
    }

    int i = blk * 256 + t;
    if (i < N) {
        float x = sv[3*i], y = sv[3*i+1], z = sv[3*i+2];
        float k2 = fmaf(x, x, fmaf(y, y, z*z));
        int pos = atomicAdd(&cursor[bucket_of(k2)], 1);   // LDS atomic
        sorted[pos] = make_float4(x, y, z, __int_as_float(i));
    }
}

template<bool SORTED>
__global__ __launch_bounds__(WAVES * 64) void knn_loss_kernel(
    const float4* __restrict__ pts,   // sorted points (SORTED only)
    const float*  __restrict__ smax,  // suffix |p| upper bound per 64-block
    const float*  __restrict__ sv,    // [N,3] original scan vertices
    const float*  __restrict__ tv,    // [M,3]
    const float*  __restrict__ sn,    // [N,3]
    const float*  __restrict__ tn,    // [M,3]
    float* __restrict__ out, int N, int M, float invM)
{
    __shared__ float bsum[WAVES];
    const int lane = threadIdx.x & 63;
    const int w    = threadIdx.x >> 6;
    const int m    = blockIdx.x * WAVES + w;
    const bool valid = (m < M);

    float contrib = 0.0f;
    if (valid) {
        const float tvx = tv[3*m], tvy = tv[3*m+1], tvz = tv[3*m+2];
        const float tlen = sqrtf(tvx*tvx + tvy*tvy + tvz*tvz);

        // ---- bootstrap: bitonic-sort first 64 points desc by (d2, -idx) ----
        float v; int idx;
        {
            int l = (lane < N) ? lane : 0;
            float px, py, pz;
            if (SORTED) {
                float4 q = pts[l];
                px = q.x; py = q.y; pz = q.z; idx = __float_as_int(q.w);
            } else {
                px = sv[3*l]; py = sv[3*l+1]; pz = sv[3*l+2]; idx = l;
            }
            float dx = px - tvx, dy = py - tvy, dz = pz - tvz;
            v = fmaf(dx, dx, fmaf(dy, dy, dz * dz));
            if (lane >= N) { v = -1.0f; idx = 0x7FFFFFFF; }
        }
#pragma unroll
        for (int k = 2; k <= 64; k <<= 1) {
#pragma unroll
            for (int j = k >> 1; j > 0; j >>= 1) {
                float ov = __shfl_xor(v, j);
                int   oi = __shfl_xor(idx, j);
                bool up    = ((lane & k) == 0);   // descending segment
                bool lower = ((lane & j) == 0);
                bool mine  = (v > ov) || (v == ov && idx < oi); // total order
                bool keep  = lower ? (up ? mine : !mine) : (up ? !mine : mine);
                if (!keep) { v = ov; idx = oi; }
            }
        }
        // lanes 0..K-1 now hold the exact top-K of the first 64 (sorted desc)
        float eV = (lane < K) ? v : -1.0f;
        int   eI = idx;
        float thr = __shfl(v, K - 1);   // current 15th-largest d2

        // ---- main scan ----
        for (int ib = 64; ib < N; ib += 64) {
            if (SORTED) {
                float bnd = smax[ib >> 6] + tlen;      // upper bound on remaining d
                if (bnd * bnd * 1.00001f < thr) break; // margin covers fp rounding
            }
            int  i   = ib + lane;
            bool has = (i < N);
            float d2; int oi2;
            if (SORTED) {
                float4 q = pts[has ? i : 0];
                float dx = q.x - tvx, dy = q.y - tvy, dz = q.z - tvz;
                d2 = fmaf(dx, dx, fmaf(dy, dy, dz * dz));
                oi2 = __float_as_int(q.w);
            } else {
                int g = has ? i : 0;
                float dx = sv[3*g] - tvx, dy = sv[3*g+1] - tvy, dz = sv[3*g+2] - tvz;
                d2 = fmaf(dx, dx, fmaf(dy, dy, dz * dz));
                oi2 = i;
            }
            // >= : an equal-d2 candidate with lower original idx must displace
            unsigned long long mb = __ballot(has && (d2 >= thr));
            while (mb) {
                int src = __ffsll(mb) - 1;
                mb &= mb - 1;
                float cv = __shfl(d2, src);
                int   ci = __shfl(oi2, src);
                // position = #entries strictly better than candidate
                unsigned long long bb =
                    __ballot((eV > cv) || (eV == cv && eI < ci)) & 0x7FFFull;
                int p = __popcll(bb);
                if (p < K) {   // wave-uniform
                    float uv = __shfl_up(eV, 1);
                    int   ui = __shfl_up(eI, 1);
                    if (lane < K) {
                        if (lane == p)      { eV = cv; eI = ci; }
                        else if (lane > p)  { eV = uv; eI = ui; }
                    }
                    // tighten thr NOW and prune doomed candidates (the round-4
                    // avalanche). >= keeps exact tie semantics; &= only clears
                    // bits so has==false lanes can't re-enter.
                    thr = __shfl(eV, K - 1);
                    if (mb) mb &= __ballot(d2 >= thr);
                }
            }
        }

        // ---- epilogue: argmin angle, tie-break by top-k rank (= lane) ----
        const float tnx = tn[3*m], tny = tn[3*m+1], tnz = tn[3*m+2];
        float ang = 3.0e38f;
        int myI = eI;
        if (lane < K && myI != 0x7FFFFFFF) {
            float dot = sn[3*myI]*tnx + sn[3*myI+1]*tny + sn[3*myI+2]*tnz;
            dot = fminf(1.0f, fmaxf(-1.0f, dot));
            ang = acosf(dot) * 57.29577951308232f;   // degrees, matches jnp
        }
        // entries live in lanes 0..14 -> reduce within the 16-lane group
        float ba = ang; int br = lane; int bi = myI;
#pragma unroll
        for (int s = 1; s < 16; s <<= 1) {
            float oa  = __shfl_xor(ba, s);
            int   orr = __shfl_xor(br, s);
            int   oi  = __shfl_xor(bi, s);
            bool take = (oa < ba) || (oa == ba && orr < br);
            if (take) { ba = oa; br = orr; bi = oi; }
        }
        if (lane == 0) {
            float dx = sv[3*bi]   - tvx;
            float dy = sv[3*bi+1] - tvy;
            float dz = sv[3*bi+2] - tvz;
            contrib = sqrtf(dx*dx + dy*dy + dz*dz) * invM;
        }
    }

    if (lane == 0) bsum[w] = contrib;
    __syncthreads();
    if (threadIdx.x == 0) {
        float s = 0.0f;
#pragma unroll
        for (int i = 0; i < WAVES; ++i) s += bsum[i];
        atomicAdd(out, s);
    }
}

extern "C" void kernel_launch(void* const* d_in, const int* in_sizes, int n_in,
                              void* d_out, int out_size, void* d_ws, size_t ws_size,
                              hipStream_t stream) {
    const float* sv = (const float*)d_in[0];   // scan_vertices   [1,N,3]
    const float* tv = (const float*)d_in[1];   // template_vertices [1,M,3]
    const float* sn = (const float*)d_in[2];   // scan_normals    [N,3]
    const float* tn = (const float*)d_in[3];   // template_normals [M,3]
    // d_in[4] = K_knn (fixed 15, compile-time)

    int N = in_sizes[0] / 3;
    int M = in_sizes[1] / 3;
    int nb = (N + 63) / 64;
    float* out = (float*)d_out;
    float invM = 1.0f / (float)M;
    int grid  = (M + WAVES - 1) / WAVES;
    int nblk  = (N + 255) / 256;

    // d_ws layout: [sorted float4 x N][smax x nb][blkhist x nblk*256]
    size_t offSorted = 0;
    size_t offSmax   = offSorted + (size_t)N * sizeof(float4);
    size_t offHist   = (offSmax + (size_t)nb * sizeof(float) + 15) & ~(size_t)15;
    size_t need      = offHist + (size_t)nblk * NBUCK * sizeof(int);

    if (ws_size >= need) {
        float4* sorted  = (float4*)((char*)d_ws + offSorted);
        float*  smax    = (float*) ((char*)d_ws + offSmax);
        int*    blkhist = (int*)   ((char*)d_ws + offHist);

        hist_kernel        <<<nblk, 256, 0, stream>>>(sv, blkhist, N);
        scan_scatter_kernel<<<nblk, 256, 0, stream>>>(sv, blkhist, sorted,
                                                      smax, out, N, nb, nblk);
        knn_loss_kernel<true><<<grid, WAVES * 64, 0, stream>>>(
            sorted, smax, sv, tv, sn, tn, out, N, M, invM);
    } else {
        zero_out_kernel<<<1, 1, 0, stream>>>(out);
        knn_loss_kernel<false><<<grid, WAVES * 64, 0, stream>>>(
            nullptr, nullptr, sv, tv, sn, tn, out, N, M, invM);
    }
}

// Round 6
// 83.316 us; speedup vs baseline: 1.9049x; 1.1713x over previous
//
#include <hip/hip_runtime.h>
#include <math.h>

// NormalLoss: for each template vertex (M=6890), take the K=15 scan points
// (N=20000) with LARGEST distance, among them pick the min-angle normal
// match, loss = mean ||sv[sel]-tv||.
//
// Round-6 design (round-5 ledger pins ~25-35 us on the 1723-block
// same-address atomicAdd(out) tail -- L2 serializes same-address RMWs):
//  * main kernel writes per-block partials to d_ws (full overwrite,
//    poison-safe); new 1-block reduce_kernel sums partials -> out[0].
//    No atomics, no zeroing kernel/dependency anywhere.
//  * scan loop issues point loads BEFORE the smax break check so the
//    scalar smax load overlaps the vector loads.
//  * pipeline otherwise identical to round 5 (absmax 0.0 x4): hist (LDS,
//    per-block rows) -> scan_scatter (redundant scan, LDS cursors) ->
//    main (bitonic bootstrap, sorted wave top-K, thr re-tightened after
//    every insert, early break when (suffixBound|p|+|tv|)^2 < 15th d^2)
//    -> reduce.

constexpr int K = 15;
constexpr int NBUCK = 256;
constexpr int WAVES = 4;     // waves (=vertices) per block in main kernel

__device__ __forceinline__ int bucket_of(float k2) {
    int b = (int)(k2 * 8.0f);           // 0.125-wide buckets over |p|^2 in [0,32)
    b = b > (NBUCK - 1) ? (NBUCK - 1) : b;
    return (NBUCK - 1) - b;             // bucket 0 = largest |p|
}

__global__ __launch_bounds__(256) void hist_kernel(
    const float* __restrict__ sv, int* __restrict__ blkhist, int N)
{
    __shared__ int h[NBUCK];
    int t = threadIdx.x;
    h[t] = 0;
    __syncthreads();
    int i = blockIdx.x * 256 + t;
    if (i < N) {
        float x = sv[3*i], y = sv[3*i+1], z = sv[3*i+2];
        atomicAdd(&h[bucket_of(fmaf(x, x, fmaf(y, y, z*z)))], 1);
    }
    __syncthreads();
    blkhist[blockIdx.x * NBUCK + t] = h[t];   // full-row overwrite (poison-safe)
}

__global__ __launch_bounds__(256) void scan_scatter_kernel(
    const float* __restrict__ sv,
    const int*   __restrict__ blkhist,  // [nblk][NBUCK]
    float4*      __restrict__ sorted,   // [N] out: (x,y,z,bitcast(origIdx))
    float*       __restrict__ smax,     // [nb] out: |p| upper bound at pos >= j*64
    int N, int nb, int nblk)
{
    __shared__ int tmp[NBUCK];
    __shared__ int startSh[NBUCK];
    __shared__ int cursor[NBUCK];
    const int t   = threadIdx.x;
    const int blk = blockIdx.x;

    // column sums over blocks (coalesced row reads); unrolled so the L2
    // loads pipeline instead of serializing on latency
    int mine = 0, total = 0;
#pragma unroll 8
    for (int b = 0; b < nblk; ++b) {
        int v = blkhist[b * NBUCK + t];
        if (b < blk) mine += v;
        total += v;
    }
    tmp[t] = total;
    __syncthreads();
    // Kogge-Stone inclusive scan over buckets
    for (int d = 1; d < NBUCK; d <<= 1) {
        int u = (t >= d) ? tmp[t - d] : 0;
        __syncthreads();
        tmp[t] += u;
        __syncthreads();
    }
    int startv = tmp[t] - total;        // exclusive bucket start
    startSh[t] = startv;
    cursor[t]  = startv + mine;         // this block's write base per bucket
    __syncthreads();

    if (blk == 0) {
        // smax[j]: position j*64 lies in flipped bucket fb (largest fb with
        // start[fb] <= pos); all points at pos >= j*64 have original bucket
        // <= (NBUCK-1)-fb, so |p| <= sqrt(upper edge). Exact upper bound,
        // independent of within-bucket order.
        for (int j = t; j < nb; j += 256) {
            int pos = j * 64;
            int lo = 0, hi = NBUCK - 1;
            while (lo < hi) {
                int mid = (lo + hi + 1) >> 1;
                if (startSh[mid] <= pos) lo = mid; else hi = mid - 1;
            }
            int bOrig = (NBUCK - 1) - lo;
            smax[j] = sqrtf((float)(bOrig + 1) * 0.125f);
        }
    }

    int i = blk * 256 + t;
    if (i < N) {
        float x = sv[3*i], y = sv[3*i+1], z = sv[3*i+2];
        float k2 = fmaf(x, x, fmaf(y, y, z*z));
        int pos = atomicAdd(&cursor[bucket_of(k2)], 1);   // LDS atomic
        sorted[pos] = make_float4(x, y, z, __int_as_float(i));
    }
}

template<bool SORTED>
__global__ __launch_bounds__(WAVES * 64) void knn_loss_kernel(
    const float4* __restrict__ pts,   // sorted points (SORTED only)
    const float*  __restrict__ smax,  // suffix |p| upper bound per 64-block
    const float*  __restrict__ sv,    // [N,3] original scan vertices
    const float*  __restrict__ tv,    // [M,3]
    const float*  __restrict__ sn,    // [N,3]
    const float*  __restrict__ tn,    // [M,3]
    float* __restrict__ partial,      // [gridDim.x] per-block sums (no atomics)
    int N, int M, float invM)
{
    __shared__ float bsum[WAVES];
    const int lane = threadIdx.x & 63;
    const int w    = threadIdx.x >> 6;
    const int m    = blockIdx.x * WAVES + w;
    const bool valid = (m < M);

    float contrib = 0.0f;
    if (valid) {
        const float tvx = tv[3*m], tvy = tv[3*m+1], tvz = tv[3*m+2];
        const float tlen = sqrtf(tvx*tvx + tvy*tvy + tvz*tvz);

        // ---- bootstrap: bitonic-sort first 64 points desc by (d2, -idx) ----
        float v; int idx;
        {
            int l = (lane < N) ? lane : 0;
            float px, py, pz;
            if (SORTED) {
                float4 q = pts[l];
                px = q.x; py = q.y; pz = q.z; idx = __float_as_int(q.w);
            } else {
                px = sv[3*l]; py = sv[3*l+1]; pz = sv[3*l+2]; idx = l;
            }
            float dx = px - tvx, dy = py - tvy, dz = pz - tvz;
            v = fmaf(dx, dx, fmaf(dy, dy, dz * dz));
            if (lane >= N) { v = -1.0f; idx = 0x7FFFFFFF; }
        }
#pragma unroll
        for (int k = 2; k <= 64; k <<= 1) {
#pragma unroll
            for (int j = k >> 1; j > 0; j >>= 1) {
                float ov = __shfl_xor(v, j);
                int   oi = __shfl_xor(idx, j);
                bool up    = ((lane & k) == 0);   // descending segment
                bool lower = ((lane & j) == 0);
                bool mine  = (v > ov) || (v == ov && idx < oi); // total order
                bool keep  = lower ? (up ? mine : !mine) : (up ? !mine : mine);
                if (!keep) { v = ov; idx = oi; }
            }
        }
        // lanes 0..K-1 now hold the exact top-K of the first 64 (sorted desc)
        float eV = (lane < K) ? v : -1.0f;
        int   eI = idx;
        float thr = __shfl(v, K - 1);   // current 15th-largest d2

        // ---- main scan ----
        for (int ib = 64; ib < N; ib += 64) {
            int  i   = ib + lane;
            bool has = (i < N);
            // issue point loads FIRST so they overlap the smax scalar load;
            // a wasted prefetch on break is harmless
            float d2; int oi2;
            if (SORTED) {
                float4 q = pts[has ? i : 0];
                float bnd = smax[ib >> 6] + tlen;      // upper bound on remaining d
                if (bnd * bnd * 1.00001f < thr) break; // margin covers fp rounding
                float dx = q.x - tvx, dy = q.y - tvy, dz = q.z - tvz;
                d2 = fmaf(dx, dx, fmaf(dy, dy, dz * dz));
                oi2 = __float_as_int(q.w);
            } else {
                int g = has ? i : 0;
                float dx = sv[3*g] - tvx, dy = sv[3*g+1] - tvy, dz = sv[3*g+2] - tvz;
                d2 = fmaf(dx, dx, fmaf(dy, dy, dz * dz));
                oi2 = i;
            }
            // >= : an equal-d2 candidate with lower original idx must displace
            unsigned long long mb = __ballot(has && (d2 >= thr));
            while (mb) {
                int src = __ffsll(mb) - 1;
                mb &= mb - 1;
                float cv = __shfl(d2, src);
                int   ci = __shfl(oi2, src);
                // position = #entries strictly better than candidate
                unsigned long long bb =
                    __ballot((eV > cv) || (eV == cv && eI < ci)) & 0x7FFFull;
                int p = __popcll(bb);
                if (p < K) {   // wave-uniform
                    float uv = __shfl_up(eV, 1);
                    int   ui = __shfl_up(eI, 1);
                    if (lane < K) {
                        if (lane == p)      { eV = cv; eI = ci; }
                        else if (lane > p)  { eV = uv; eI = ui; }
                    }
                    // tighten thr NOW and prune doomed candidates. >= keeps
                    // exact tie semantics; &= only clears bits so has==false
                    // lanes can't re-enter.
                    thr = __shfl(eV, K - 1);
                    if (mb) mb &= __ballot(d2 >= thr);
                }
            }
        }

        // ---- epilogue: argmin angle, tie-break by top-k rank (= lane) ----
        const float tnx = tn[3*m], tny = tn[3*m+1], tnz = tn[3*m+2];
        float ang = 3.0e38f;
        int myI = eI;
        if (lane < K && myI != 0x7FFFFFFF) {
            float dot = sn[3*myI]*tnx + sn[3*myI+1]*tny + sn[3*myI+2]*tnz;
            dot = fminf(1.0f, fmaxf(-1.0f, dot));
            ang = acosf(dot) * 57.29577951308232f;   // degrees, matches jnp
        }
        // entries live in lanes 0..14 -> reduce within the 16-lane group
        float ba = ang; int br = lane; int bi = myI;
#pragma unroll
        for (int s = 1; s < 16; s <<= 1) {
            float oa  = __shfl_xor(ba, s);
            int   orr = __shfl_xor(br, s);
            int   oi  = __shfl_xor(bi, s);
            bool take = (oa < ba) || (oa == ba && orr < br);
            if (take) { ba = oa; br = orr; bi = oi; }
        }
        if (lane == 0) {
            float dx = sv[3*bi]   - tvx;
            float dy = sv[3*bi+1] - tvy;
            float dz = sv[3*bi+2] - tvz;
            contrib = sqrtf(dx*dx + dy*dy + dz*dz) * invM;
        }
    }

    if (lane == 0) bsum[w] = contrib;
    __syncthreads();
    if (threadIdx.x == 0)
        partial[blockIdx.x] = bsum[0] + bsum[1] + bsum[2] + bsum[3];
}

__global__ __launch_bounds__(256) void reduce_kernel(
    const float* __restrict__ partial, float* __restrict__ out, int n)
{
    __shared__ float sh[4];
    const int lane = threadIdx.x & 63;
    const int w    = threadIdx.x >> 6;
    float s = 0.0f;
    for (int i = threadIdx.x; i < n; i += 256) s += partial[i];
#pragma unroll
    for (int d = 1; d < 64; d <<= 1) s += __shfl_xor(s, d);
    if (lane == 0) sh[w] = s;
    __syncthreads();
    if (threadIdx.x == 0) out[0] = sh[0] + sh[1] + sh[2] + sh[3];
}

extern "C" void kernel_launch(void* const* d_in, const int* in_sizes, int n_in,
                              void* d_out, int out_size, void* d_ws, size_t ws_size,
                              hipStream_t stream) {
    const float* sv = (const float*)d_in[0];   // scan_vertices   [1,N,3]
    const float* tv = (const float*)d_in[1];   // template_vertices [1,M,3]
    const float* sn = (const float*)d_in[2];   // scan_normals    [N,3]
    const float* tn = (const float*)d_in[3];   // template_normals [M,3]
    // d_in[4] = K_knn (fixed 15, compile-time)

    int N = in_sizes[0] / 3;
    int M = in_sizes[1] / 3;
    int nb = (N + 63) / 64;
    float* out = (float*)d_out;
    float invM = 1.0f / (float)M;
    int grid  = (M + WAVES - 1) / WAVES;
    int nblk  = (N + 255) / 256;

    // d_ws layout: [sorted float4 x N][smax x nb][blkhist x nblk*256][partial x grid]
    size_t offSorted  = 0;
    size_t offSmax    = offSorted + (size_t)N * sizeof(float4);
    size_t offHist    = (offSmax + (size_t)nb * sizeof(float) + 15) & ~(size_t)15;
    size_t offPartial = offHist + (size_t)nblk * NBUCK * sizeof(int);
    size_t need       = offPartial + (size_t)grid * sizeof(float);

    if (ws_size >= need) {
        float4* sorted  = (float4*)((char*)d_ws + offSorted);
        float*  smax    = (float*) ((char*)d_ws + offSmax);
        int*    blkhist = (int*)   ((char*)d_ws + offHist);
        float*  partial = (float*) ((char*)d_ws + offPartial);

        hist_kernel        <<<nblk, 256, 0, stream>>>(sv, blkhist, N);
        scan_scatter_kernel<<<nblk, 256, 0, stream>>>(sv, blkhist, sorted,
                                                      smax, N, nb, nblk);
        knn_loss_kernel<true><<<grid, WAVES * 64, 0, stream>>>(
            sorted, smax, sv, tv, sn, tn, partial, N, M, invM);
        reduce_kernel      <<<1, 256, 0, stream>>>(partial, out, grid);
    } else if (ws_size >= (size_t)grid * sizeof(float)) {
        float* partial = (float*)d_ws;
        knn_loss_kernel<false><<<grid, WAVES * 64, 0, stream>>>(
            nullptr, nullptr, sv, tv, sn, tn, partial, N, M, invM);
        reduce_kernel      <<<1, 256, 0, stream>>>(partial, out, grid);
    }
}